// Round 1
// baseline (1175.349 us; speedup 1.0000x reference)
//
#include <hip/hip_runtime.h>

#define B_ 128
#define T_ 1024
#define I_ 128
#define H_ 256
#define O_ 64

// ---------------------------------------------------------------------------
// Phase A: xw[row, j] = sum_i x[row, i] * W_xh[j, i] + b_h[j]
//   row = b*T + t   (131072 rows, K=128, N=256)
// 512 blocks x 256 threads. W_xh (32768 fp32) register-resident:
//   lane (jb = tid&31, kb = tid>>5 in [0,8)) holds W_xh[jb*8+a][kb*16+c],
//   a<8, c<16  -> 128 VGPRs.  k-partials reduced via swizzled LDS buffer.
// ---------------------------------------------------------------------------
__global__ __launch_bounds__(256, 2)
void xw_gemm_kernel(const float* __restrict__ x, const float* __restrict__ W_xh,
                    const float* __restrict__ b_h, float* __restrict__ xw)
{
    const int tid = threadIdx.x;
    const int jb  = tid & 31;
    const int kb  = tid >> 5;                 // 0..7
    __shared__ __align__(16) float part[8 * 256];

    // register-resident W_xh tile
    float4 wa[8][4];
#pragma unroll
    for (int a = 0; a < 8; ++a) {
        const float* wrow = W_xh + (size_t)(jb * 8 + a) * I_ + kb * 16;
#pragma unroll
        for (int c4 = 0; c4 < 4; ++c4)
            wa[a][c4] = reinterpret_cast<const float4*>(wrow)[c4];
    }
    const float bh = b_h[tid];

    const int rowsPerWG = (B_ * T_) / 512;    // 256
    const int base = blockIdx.x * rowsPerWG;

    float4 xr[4], xn[4];
    {
        const float4* xp = reinterpret_cast<const float4*>(
            x + (size_t)base * I_ + kb * 16);
#pragma unroll
        for (int c4 = 0; c4 < 4; ++c4) { xr[c4] = xp[c4]; xn[c4] = xr[c4]; }
    }

    for (int rr = 0; rr < rowsPerWG; ++rr) {
        const int row = base + rr;
        if (rr + 1 < rowsPerWG) {             // prefetch next row (registers)
            const float4* xp = reinterpret_cast<const float4*>(
                x + (size_t)(row + 1) * I_ + kb * 16);
#pragma unroll
            for (int c4 = 0; c4 < 4; ++c4) xn[c4] = xp[c4];
        }

        float acc[8];
#pragma unroll
        for (int a = 0; a < 8; ++a) acc[a] = 0.f;
#pragma unroll
        for (int c4 = 0; c4 < 4; ++c4) {
            const float4 xv = xr[c4];
#pragma unroll
            for (int a = 0; a < 8; ++a) {
                const float4 wv = wa[a][c4];
                acc[a] = fmaf(xv.x, wv.x, acc[a]);
                acc[a] = fmaf(xv.y, wv.y, acc[a]);
                acc[a] = fmaf(xv.z, wv.z, acc[a]);
                acc[a] = fmaf(xv.w, wv.w, acc[a]);
            }
        }
        // swizzled partial write: quad q = jb*2+u, col-quad q^kb (conflict-free)
        float4* p4 = reinterpret_cast<float4*>(part);
        p4[kb * 64 + ((jb * 2 + 0) ^ kb)] = make_float4(acc[0], acc[1], acc[2], acc[3]);
        p4[kb * 64 + ((jb * 2 + 1) ^ kb)] = make_float4(acc[4], acc[5], acc[6], acc[7]);
        __syncthreads();
        {
            const int q = tid >> 2, m = tid & 3;
            float s = 0.f;
#pragma unroll
            for (int g = 0; g < 8; ++g)
                s += part[g * 256 + (((q ^ g) << 2) | m)];
            xw[(size_t)row * H_ + tid] = s + bh;   // coalesced 1 KB store
        }
        __syncthreads();
#pragma unroll
        for (int c4 = 0; c4 < 4; ++c4) xr[c4] = xn[c4];
    }
}

// ---------------------------------------------------------------------------
// Phase B: fused recurrence + output projection. One WG (512 thr) per batch row.
//   h_t = relu(xw_t + h_{t-1} @ W_hh^T);  out_t = h_t @ W_out^T + b_out
// W_hh (65536 fp32) register-resident: lane (jb=tid&31, kb=tid>>5 in [0,16))
//   holds W_hh[jb*8+a][kb*16+c] -> 128 VGPRs.  W_out: 32 VGPRs/lane.
// k-partials reduced via XOR-swizzled LDS buffer; 3 barriers/step.
// xw streamed from ws with depth-2 register prefetch (covers HBM latency).
// ---------------------------------------------------------------------------
__global__ __launch_bounds__(512, 2)
void rnn_scan_kernel(const float* __restrict__ xw, const float* __restrict__ W_hh,
                     const float* __restrict__ W_out, const float* __restrict__ b_out,
                     float* __restrict__ out)
{
    const int tid = threadIdx.x;
    const int jb  = tid & 31;
    const int kb  = tid >> 5;                 // 0..15
    const int r   = blockIdx.x;               // batch row

    __shared__ __align__(16) float hs[H_];
    __shared__ __align__(16) float part[16 * 256];
    __shared__ __align__(16) float opart[16 * 64];

    float4 wa[8][4];
#pragma unroll
    for (int a = 0; a < 8; ++a) {
        const float* wrow = W_hh + (size_t)(jb * 8 + a) * H_ + kb * 16;
#pragma unroll
        for (int c4 = 0; c4 < 4; ++c4)
            wa[a][c4] = reinterpret_cast<const float4*>(wrow)[c4];
    }
    float4 wo[2][4];
#pragma unroll
    for (int d = 0; d < 2; ++d) {
        const float* wrow = W_out + (size_t)(jb * 2 + d) * H_ + kb * 16;
#pragma unroll
        for (int c4 = 0; c4 < 4; ++c4)
            wo[d][c4] = reinterpret_cast<const float4*>(wrow)[c4];
    }

    const float* xwrow = xw + (size_t)r * T_ * H_;
    float xwreg = 0.f, xwn1 = 0.f, xwn2 = 0.f;
    if (tid < 256) {
        xwreg = xwrow[tid];                   // t = 0
        xwn1  = xwrow[H_ + tid];              // t = 1
    }
    const float bo = (tid < 64) ? b_out[tid] : 0.f;

    float4 hr[4];                             // h_{t-1}[kb*16 .. +16)
#pragma unroll
    for (int c4 = 0; c4 < 4; ++c4) hr[c4] = make_float4(0.f, 0.f, 0.f, 0.f);

    float* outrow = out + (size_t)r * T_ * O_;

#pragma unroll 1
    for (int t = 0; t < T_; ++t) {
        // prefetch xw for t+2
        if (tid < 256) {
            const int tt = (t + 2 < T_) ? (t + 2) : (T_ - 1);
            xwn2 = xwrow[(size_t)tt * H_ + tid];
        }

        // recurrence partial dot: acc[a] = sum_c h[kb*16+c] * W_hh[jb*8+a][kb*16+c]
        float acc[8];
#pragma unroll
        for (int a = 0; a < 8; ++a) acc[a] = 0.f;
#pragma unroll
        for (int c4 = 0; c4 < 4; ++c4) {
            const float4 hv = hr[c4];
#pragma unroll
            for (int a = 0; a < 8; ++a) {
                const float4 wv = wa[a][c4];
                acc[a] = fmaf(hv.x, wv.x, acc[a]);
                acc[a] = fmaf(hv.y, wv.y, acc[a]);
                acc[a] = fmaf(hv.z, wv.z, acc[a]);
                acc[a] = fmaf(hv.w, wv.w, acc[a]);
            }
        }
        {
            float4* p4 = reinterpret_cast<float4*>(part);
            p4[kb * 64 + ((jb * 2 + 0) ^ kb)] = make_float4(acc[0], acc[1], acc[2], acc[3]);
            p4[kb * 64 + ((jb * 2 + 1) ^ kb)] = make_float4(acc[4], acc[5], acc[6], acc[7]);
        }
        __syncthreads();                      // (1) partials visible

        if (tid < 256) {                      // reduce 16 k-groups, + xw, relu
            const int q = tid >> 2, m = tid & 3;
            float s = 0.f;
#pragma unroll
            for (int g = 0; g < 16; ++g)
                s += part[g * 256 + (((q ^ g) << 2) | m)];
            s += xwreg;
            hs[tid] = (s > 0.f) ? s : 0.f;
            xwreg = xwn1; xwn1 = xwn2;        // shift prefetch pipeline
        }
        __syncthreads();                      // (2) h_t visible

        // load h_t chunk once: serves out-projection AND next step's recurrence
        {
            const float4* hs4 = reinterpret_cast<const float4*>(hs);
#pragma unroll
            for (int c4 = 0; c4 < 4; ++c4) hr[c4] = hs4[kb * 4 + c4];
        }

        // output-projection partials: o = jb*2+d
        float oa0 = 0.f, oa1 = 0.f;
#pragma unroll
        for (int c4 = 0; c4 < 4; ++c4) {
            const float4 hv = hr[c4];
            const float4 w0 = wo[0][c4], w1 = wo[1][c4];
            oa0 = fmaf(hv.x, w0.x, oa0); oa0 = fmaf(hv.y, w0.y, oa0);
            oa0 = fmaf(hv.z, w0.z, oa0); oa0 = fmaf(hv.w, w0.w, oa0);
            oa1 = fmaf(hv.x, w1.x, oa1); oa1 = fmaf(hv.y, w1.y, oa1);
            oa1 = fmaf(hv.z, w1.z, oa1); oa1 = fmaf(hv.w, w1.w, oa1);
        }
        reinterpret_cast<float2*>(opart)[kb * 32 + jb] = make_float2(oa0, oa1);
        __syncthreads();                      // (3) out-partials visible

        if (tid < 64) {
            float s = 0.f;
#pragma unroll
            for (int g = 0; g < 16; ++g) s += opart[g * 64 + tid];
            outrow[(size_t)t * O_ + tid] = s + bo;   // coalesced 256 B store
        }
    }
}

// ---------------------------------------------------------------------------
extern "C" void kernel_launch(void* const* d_in, const int* in_sizes, int n_in,
                              void* d_out, int out_size, void* d_ws, size_t ws_size,
                              hipStream_t stream)
{
    (void)in_sizes; (void)n_in; (void)out_size; (void)ws_size;
    const float* x     = (const float*)d_in[0];   // [B,T,I]
    const float* W_xh  = (const float*)d_in[1];   // [H,I]
    const float* W_hh  = (const float*)d_in[2];   // [H,H]
    const float* b_h   = (const float*)d_in[3];   // [H]
    const float* W_out = (const float*)d_in[4];   // [O,H]
    const float* b_out = (const float*)d_in[5];   // [O]
    float* out = (float*)d_out;                   // [B,T,O]
    float* xw  = (float*)d_ws;                    // [B*T*H] fp32 = 128 MiB scratch

    xw_gemm_kernel<<<512, 256, 0, stream>>>(x, W_xh, b_h, xw);
    rnn_scan_kernel<<<128, 512, 0, stream>>>(xw, W_hh, W_out, b_out, out);
}